// Round 1
// baseline (106.910 us; speedup 1.0000x reference)
//
#include <hip/hip_runtime.h>
#include <math.h>

#define B_DIM 4096
#define N_DIM 8192

__constant__ const float kCommission = 0.0025f;
__constant__ const float kInterest   = 8e-05f;

// ---------------------------------------------------------------------------
// Kernel A: per-row dot(w,y) and interest = sum(min(w*y,0)) * rate
// ---------------------------------------------------------------------------
__global__ __launch_bounds__(256) void rowdot_kernel(const float* __restrict__ w,
                                                     const float* __restrict__ y,
                                                     float* __restrict__ dot_out,
                                                     float* __restrict__ int_out) {
    const int b   = blockIdx.x;
    const int tid = threadIdx.x;
    const float4* w4 = (const float4*)(w + (size_t)b * N_DIM);
    const float4* y4 = (const float4*)(y + (size_t)b * N_DIM);

    float dot = 0.f, intr = 0.f;
    #pragma unroll
    for (int i = tid; i < N_DIM / 4; i += 256) {
        float4 wv = w4[i];
        float4 yv = y4[i];
        float e0 = wv.x * yv.x, e1 = wv.y * yv.y, e2 = wv.z * yv.z, e3 = wv.w * yv.w;
        dot  += (e0 + e1) + (e2 + e3);
        intr += (fminf(e0, 0.f) + fminf(e1, 0.f)) + (fminf(e2, 0.f) + fminf(e3, 0.f));
    }
    #pragma unroll
    for (int off = 32; off; off >>= 1) {
        dot  += __shfl_down(dot,  off);
        intr += __shfl_down(intr, off);
    }
    __shared__ float sd[4], si[4];
    const int wave = tid >> 6, lane = tid & 63;
    if (lane == 0) { sd[wave] = dot; si[wave] = intr; }
    __syncthreads();
    if (tid == 0) {
        dot_out[b] = (sd[0] + sd[1]) + (sd[2] + sd[3]);
        int_out[b] = ((si[0] + si[1]) + (si[2] + si[3])) * kInterest;
    }
}

// ---------------------------------------------------------------------------
// Kernel B: commission term + final per-row reward
//   reward[0]   = dot[0] + interest[0]
//   reward[b>0] = dot[b]*(1 - 0.0025*sum|w[b-1]*y[b-1]/dot[b-1] - w[b]|) + interest[b]
// ---------------------------------------------------------------------------
__global__ __launch_bounds__(256) void reward_kernel(const float* __restrict__ w,
                                                     const float* __restrict__ y,
                                                     const float* __restrict__ dot_in,
                                                     const float* __restrict__ int_in,
                                                     float* __restrict__ reward_out) {
    const int b = blockIdx.x;
    if (b == 0) {
        if (threadIdx.x == 0) reward_out[0] = dot_in[0] + int_in[0];
        return;
    }
    const int tid = threadIdx.x;
    const float inv_dprev = 1.0f / dot_in[b - 1];
    const float4* wp = (const float4*)(w + (size_t)(b - 1) * N_DIM);
    const float4* yp = (const float4*)(y + (size_t)(b - 1) * N_DIM);
    const float4* wc = (const float4*)(w + (size_t)b * N_DIM);

    float comm = 0.f;
    #pragma unroll
    for (int i = tid; i < N_DIM / 4; i += 256) {
        float4 wv = wp[i];
        float4 yv = yp[i];
        float4 wn = wc[i];
        comm += (fabsf(fmaf(wv.x * yv.x, inv_dprev, -wn.x)) +
                 fabsf(fmaf(wv.y * yv.y, inv_dprev, -wn.y))) +
                (fabsf(fmaf(wv.z * yv.z, inv_dprev, -wn.z)) +
                 fabsf(fmaf(wv.w * yv.w, inv_dprev, -wn.w)));
    }
    #pragma unroll
    for (int off = 32; off; off >>= 1) comm += __shfl_down(comm, off);
    __shared__ float sc[4];
    const int wave = tid >> 6, lane = tid & 63;
    if (lane == 0) sc[wave] = comm;
    __syncthreads();
    if (tid == 0) {
        float c = (sc[0] + sc[1]) + (sc[2] + sc[3]);
        float pure_pc = 1.0f - c * kCommission;
        reward_out[b] = dot_in[b] * pure_pc + int_in[b];
    }
}

// ---------------------------------------------------------------------------
// Kernel C: finalize. 1 block, 1024 threads, 4 rewards per thread.
//   loss = -mean(log r); pv_total = exp(sum log r);
//   SR = (mean(r)-1)/std(r, ddof=1)   [double two-pass];
//   MDD via log-space: S = prefix_sum(log r), M = prefix_max(S),
//        MDD = max(1 - exp(S - M)).
// ---------------------------------------------------------------------------
__global__ __launch_bounds__(1024) void finalize_kernel(const float* __restrict__ reward,
                                                        float* __restrict__ out) {
    const int T = 1024, PER = B_DIM / T;   // 4
    const int tid = threadIdx.x;
    const int lane = tid & 63, wave = tid >> 6;

    float r[PER], lc[PER];
    float csum = 0.f;
    #pragma unroll
    for (int j = 0; j < PER; ++j) {
        r[j] = reward[tid * PER + j];
        csum += logf(r[j]);
        lc[j] = csum;                       // inclusive prefix within chunk
    }

    // ---- block inclusive scan (add) of per-thread chunk sums ----
    float v = csum;
    #pragma unroll
    for (int off = 1; off < 64; off <<= 1) {
        float t = __shfl_up(v, off);
        if (lane >= off) v += t;
    }
    __shared__ float wsum[16];
    __shared__ float woff[17];
    if (lane == 63) wsum[wave] = v;
    __syncthreads();
    if (tid == 0) {
        float acc = 0.f;
        for (int i = 0; i < 16; ++i) { woff[i] = acc; acc += wsum[i]; }
        woff[16] = acc;
    }
    __syncthreads();
    float ev = __shfl_up(v, 1);
    if (lane == 0) ev = 0.f;
    const float excl = woff[wave] + ev;     // exclusive prefix for this chunk
    float S[PER];
    #pragma unroll
    for (int j = 0; j < PER; ++j) S[j] = excl + lc[j];
    const float total_logs = woff[16];

    // ---- block prefix-max over S ----
    float rm = -INFINITY;
    float cmax[PER];
    #pragma unroll
    for (int j = 0; j < PER; ++j) { rm = fmaxf(rm, S[j]); cmax[j] = rm; }
    float mv = rm;
    #pragma unroll
    for (int off = 1; off < 64; off <<= 1) {
        float t = __shfl_up(mv, off);
        if (lane >= off) mv = fmaxf(mv, t);
    }
    __shared__ float wmax[16];
    __shared__ float wmoff[16];
    if (lane == 63) wmax[wave] = mv;
    __syncthreads();
    if (tid == 0) {
        float acc = -INFINITY;
        for (int i = 0; i < 16; ++i) { wmoff[i] = acc; acc = fmaxf(acc, wmax[i]); }
    }
    __syncthreads();
    float emv = __shfl_up(mv, 1);
    if (lane == 0) emv = -INFINITY;
    const float mexcl = fmaxf(wmoff[wave], emv);

    float ddmax = 0.f;
    #pragma unroll
    for (int j = 0; j < PER; ++j) {
        float M = fmaxf(mexcl, cmax[j]);
        ddmax = fmaxf(ddmax, 1.0f - expf(S[j] - M));
    }
    #pragma unroll
    for (int off = 32; off; off >>= 1) ddmax = fmaxf(ddmax, __shfl_down(ddmax, off));
    __shared__ float wdd[16];
    if (lane == 0) wdd[wave] = ddmax;

    // ---- double-precision mean/var (two-pass) for SR ----
    double sr_ = 0.0;
    #pragma unroll
    for (int j = 0; j < PER; ++j) sr_ += (double)r[j];
    #pragma unroll
    for (int off = 32; off; off >>= 1) sr_ += __shfl_down(sr_, off);
    __shared__ double wsr[16];
    if (lane == 0) wsr[wave] = sr_;
    __syncthreads();
    __shared__ double mean_sh;
    if (tid == 0) {
        double s = 0.0;
        for (int i = 0; i < 16; ++i) s += wsr[i];
        mean_sh = s / (double)B_DIM;
    }
    __syncthreads();
    const double mean = mean_sh;
    double sq = 0.0;
    #pragma unroll
    for (int j = 0; j < PER; ++j) { double d = (double)r[j] - mean; sq += d * d; }
    #pragma unroll
    for (int off = 32; off; off >>= 1) sq += __shfl_down(sq, off);
    __shared__ double wsq[16];
    if (lane == 0) wsq[wave] = sq;
    __syncthreads();

    if (tid == 0) {
        double s = 0.0;
        for (int i = 0; i < 16; ++i) s += wsq[i];
        double var = s / (double)(B_DIM - 1);
        double SR = (mean - 1.0) / sqrt(var);
        float mdd = 0.f;
        for (int i = 0; i < 16; ++i) mdd = fmaxf(mdd, wdd[i]);
        out[0] = -total_logs / (float)B_DIM;   // loss
        out[1] = expf(total_logs);             // portfolio_value = prod(reward)
        out[2] = (float)SR;                    // SR
        out[3] = mdd;                          // MDD
    }
}

// ---------------------------------------------------------------------------
extern "C" void kernel_launch(void* const* d_in, const int* in_sizes, int n_in,
                              void* d_out, int out_size, void* d_ws, size_t ws_size,
                              hipStream_t stream) {
    const float* w = (const float*)d_in[0];   // (B,1,N)
    const float* y = (const float*)d_in[1];   // (B,N,1)
    float* out = (float*)d_out;

    float* dot  = (float*)d_ws;               // B floats
    float* intr = dot + B_DIM;                // B floats
    float* rew  = intr + B_DIM;               // B floats

    rowdot_kernel<<<B_DIM, 256, 0, stream>>>(w, y, dot, intr);
    reward_kernel<<<B_DIM, 256, 0, stream>>>(w, y, dot, intr, rew);
    finalize_kernel<<<1, 1024, 0, stream>>>(rew, out);
}

// Round 2
// 58.060 us; speedup vs baseline: 1.8414x; 1.8414x over previous
//
#include <hip/hip_runtime.h>
#include <math.h>

#define B_DIM 4096
#define N_DIM 8192
#define K_ROWS 4          // output rows per block
#define NBLK (B_DIM / K_ROWS)

__constant__ const float kCommission = 0.0025f;
__constant__ const float kInterest   = 8e-05f;

// ---------------------------------------------------------------------------
// Fused kernel: block i produces reward[4i .. 4i+3].
// Per row r: dot[r] = sum(w[r]*y[r]); interest[r] = sum(min(w*y,0))*rate;
//            comm[r] = sum |e[r-1]/dot[r-1] - w[r]|  (r>0)
//            reward[r] = dot[r]*(1 - 0.0025*comm[r]) + interest[r]
// e[r-1] is kept in registers between row phases; dot[r-1] comes from the
// previous phase's block reduction (redundantly recomputed for the block's
// leading boundary row).
// ---------------------------------------------------------------------------
__global__ __launch_bounds__(256) void fused_reward_kernel(const float* __restrict__ w,
                                                           const float* __restrict__ y,
                                                           float* __restrict__ reward_out) {
    const int s    = blockIdx.x * K_ROWS;     // first output row of this block
    const int tid  = threadIdx.x;
    const int lane = tid & 63, wave = tid >> 6;
    __shared__ float red[4][3];

    float4 e_prev[8];
    #pragma unroll
    for (int j = 0; j < 8; ++j) e_prev[j] = make_float4(0.f, 0.f, 0.f, 0.f);
    float inv_dprev = 0.f;

    // ---- prep phase: boundary row s-1 (dot + e only) ----
    if (s > 0) {
        const float4* wp = (const float4*)(w + (size_t)(s - 1) * N_DIM);
        const float4* yp = (const float4*)(y + (size_t)(s - 1) * N_DIM);
        float4 wv[8], yv[8];
        #pragma unroll
        for (int j = 0; j < 8; ++j) wv[j] = wp[tid + 256 * j];
        #pragma unroll
        for (int j = 0; j < 8; ++j) yv[j] = yp[tid + 256 * j];
        float d = 0.f;
        #pragma unroll
        for (int j = 0; j < 8; ++j) {
            float4 ev;
            ev.x = wv[j].x * yv[j].x; ev.y = wv[j].y * yv[j].y;
            ev.z = wv[j].z * yv[j].z; ev.w = wv[j].w * yv[j].w;
            d += (ev.x + ev.y) + (ev.z + ev.w);
            e_prev[j] = ev;
        }
        #pragma unroll
        for (int off = 32; off; off >>= 1) d += __shfl_down(d, off);
        if (lane == 0) red[wave][0] = d;
        __syncthreads();
        float dot_prev = (red[0][0] + red[1][0]) + (red[2][0] + red[3][0]);
        inv_dprev = 1.0f / dot_prev;
        __syncthreads();
    }

    // ---- main phases: rows s .. s+K_ROWS-1 ----
    #pragma unroll 1
    for (int k = 0; k < K_ROWS; ++k) {
        const int r = s + k;
        const float4* wp = (const float4*)(w + (size_t)r * N_DIM);
        const float4* yp = (const float4*)(y + (size_t)r * N_DIM);
        float4 wv[8], yv[8];
        #pragma unroll
        for (int j = 0; j < 8; ++j) wv[j] = wp[tid + 256 * j];
        #pragma unroll
        for (int j = 0; j < 8; ++j) yv[j] = yp[tid + 256 * j];

        float d = 0.f, it = 0.f, cm = 0.f;
        #pragma unroll
        for (int j = 0; j < 8; ++j) {
            float4 ev;
            ev.x = wv[j].x * yv[j].x; ev.y = wv[j].y * yv[j].y;
            ev.z = wv[j].z * yv[j].z; ev.w = wv[j].w * yv[j].w;
            d  += (ev.x + ev.y) + (ev.z + ev.w);
            it += (fminf(ev.x, 0.f) + fminf(ev.y, 0.f)) +
                  (fminf(ev.z, 0.f) + fminf(ev.w, 0.f));
            cm += (fabsf(fmaf(e_prev[j].x, inv_dprev, -wv[j].x)) +
                   fabsf(fmaf(e_prev[j].y, inv_dprev, -wv[j].y))) +
                  (fabsf(fmaf(e_prev[j].z, inv_dprev, -wv[j].z)) +
                   fabsf(fmaf(e_prev[j].w, inv_dprev, -wv[j].w)));
            e_prev[j] = ev;
        }
        #pragma unroll
        for (int off = 32; off; off >>= 1) {
            d  += __shfl_down(d,  off);
            it += __shfl_down(it, off);
            cm += __shfl_down(cm, off);
        }
        if (lane == 0) { red[wave][0] = d; red[wave][1] = it; red[wave][2] = cm; }
        __syncthreads();
        const float dot_r = (red[0][0] + red[1][0]) + (red[2][0] + red[3][0]);
        const float int_r = ((red[0][1] + red[1][1]) + (red[2][1] + red[3][1])) * kInterest;
        const float comm  = (red[0][2] + red[1][2]) + (red[2][2] + red[3][2]);
        const float pc = (r == 0) ? 1.0f : fmaf(-comm, kCommission, 1.0f);
        if (tid == 0) reward_out[r] = dot_r * pc + int_r;
        inv_dprev = 1.0f / dot_r;
        __syncthreads();
    }
}

// ---------------------------------------------------------------------------
// Finalize (unchanged from passing round): 1 block, 1024 threads.
// ---------------------------------------------------------------------------
__global__ __launch_bounds__(1024) void finalize_kernel(const float* __restrict__ reward,
                                                        float* __restrict__ out) {
    const int T = 1024, PER = B_DIM / T;   // 4
    const int tid = threadIdx.x;
    const int lane = tid & 63, wave = tid >> 6;

    float r[PER], lc[PER];
    float csum = 0.f;
    #pragma unroll
    for (int j = 0; j < PER; ++j) {
        r[j] = reward[tid * PER + j];
        csum += logf(r[j]);
        lc[j] = csum;
    }

    // block inclusive scan of per-thread log sums
    float v = csum;
    #pragma unroll
    for (int off = 1; off < 64; off <<= 1) {
        float t = __shfl_up(v, off);
        if (lane >= off) v += t;
    }
    __shared__ float wsum[16];
    __shared__ float woff[17];
    if (lane == 63) wsum[wave] = v;
    __syncthreads();
    if (tid == 0) {
        float acc = 0.f;
        for (int i = 0; i < 16; ++i) { woff[i] = acc; acc += wsum[i]; }
        woff[16] = acc;
    }
    __syncthreads();
    float ev = __shfl_up(v, 1);
    if (lane == 0) ev = 0.f;
    const float excl = woff[wave] + ev;
    float S[PER];
    #pragma unroll
    for (int j = 0; j < PER; ++j) S[j] = excl + lc[j];
    const float total_logs = woff[16];

    // block prefix-max over S
    float rm = -INFINITY;
    float cmax[PER];
    #pragma unroll
    for (int j = 0; j < PER; ++j) { rm = fmaxf(rm, S[j]); cmax[j] = rm; }
    float mv = rm;
    #pragma unroll
    for (int off = 1; off < 64; off <<= 1) {
        float t = __shfl_up(mv, off);
        if (lane >= off) mv = fmaxf(mv, t);
    }
    __shared__ float wmax[16];
    __shared__ float wmoff[16];
    if (lane == 63) wmax[wave] = mv;
    __syncthreads();
    if (tid == 0) {
        float acc = -INFINITY;
        for (int i = 0; i < 16; ++i) { wmoff[i] = acc; acc = fmaxf(acc, wmax[i]); }
    }
    __syncthreads();
    float emv = __shfl_up(mv, 1);
    if (lane == 0) emv = -INFINITY;
    const float mexcl = fmaxf(wmoff[wave], emv);

    float ddmax = 0.f;
    #pragma unroll
    for (int j = 0; j < PER; ++j) {
        float M = fmaxf(mexcl, cmax[j]);
        ddmax = fmaxf(ddmax, 1.0f - expf(S[j] - M));
    }
    #pragma unroll
    for (int off = 32; off; off >>= 1) ddmax = fmaxf(ddmax, __shfl_down(ddmax, off));
    __shared__ float wdd[16];
    if (lane == 0) wdd[wave] = ddmax;

    // double-precision two-pass mean/var for SR
    double sr_ = 0.0;
    #pragma unroll
    for (int j = 0; j < PER; ++j) sr_ += (double)r[j];
    #pragma unroll
    for (int off = 32; off; off >>= 1) sr_ += __shfl_down(sr_, off);
    __shared__ double wsr[16];
    if (lane == 0) wsr[wave] = sr_;
    __syncthreads();
    __shared__ double mean_sh;
    if (tid == 0) {
        double sm = 0.0;
        for (int i = 0; i < 16; ++i) sm += wsr[i];
        mean_sh = sm / (double)B_DIM;
    }
    __syncthreads();
    const double mean = mean_sh;
    double sq = 0.0;
    #pragma unroll
    for (int j = 0; j < PER; ++j) { double dd = (double)r[j] - mean; sq += dd * dd; }
    #pragma unroll
    for (int off = 32; off; off >>= 1) sq += __shfl_down(sq, off);
    __shared__ double wsq[16];
    if (lane == 0) wsq[wave] = sq;
    __syncthreads();

    if (tid == 0) {
        double sm = 0.0;
        for (int i = 0; i < 16; ++i) sm += wsq[i];
        double var = sm / (double)(B_DIM - 1);
        double SR = (mean - 1.0) / sqrt(var);
        float mdd = 0.f;
        for (int i = 0; i < 16; ++i) mdd = fmaxf(mdd, wdd[i]);
        out[0] = -total_logs / (float)B_DIM;
        out[1] = expf(total_logs);
        out[2] = (float)SR;
        out[3] = mdd;
    }
}

// ---------------------------------------------------------------------------
extern "C" void kernel_launch(void* const* d_in, const int* in_sizes, int n_in,
                              void* d_out, int out_size, void* d_ws, size_t ws_size,
                              hipStream_t stream) {
    const float* w = (const float*)d_in[0];   // (B,1,N)
    const float* y = (const float*)d_in[1];   // (B,N,1)
    float* out = (float*)d_out;
    float* rew = (float*)d_ws;                // B floats

    fused_reward_kernel<<<NBLK, 256, 0, stream>>>(w, y, rew);
    finalize_kernel<<<1, 1024, 0, stream>>>(rew, out);
}

// Round 3
// 50.701 us; speedup vs baseline: 2.1086x; 1.1452x over previous
//
#include <hip/hip_runtime.h>
#include <math.h>

#define B_DIM 4096
#define N_DIM 8192
#define K_ROWS 16         // output rows per block
#define NBLK (B_DIM / K_ROWS)   // 256 blocks = 1 per CU

__constant__ const float kCommission = 0.0025f;
__constant__ const float kInterest   = 8e-05f;

// ---------------------------------------------------------------------------
// Fused kernel, software-pipelined: block i produces reward[16i .. 16i+15].
// Phase k: consume staged regs (row r) -> e/dot/interest/commission partials,
// then issue row r+1's loads BEFORE the block reduction so HBM delivery
// overlaps the shfl/LDS/barrier chain. red[] double-buffered: 1 barrier/phase.
// ---------------------------------------------------------------------------
__global__ __launch_bounds__(256) void fused_reward_kernel(const float* __restrict__ w,
                                                           const float* __restrict__ y,
                                                           float* __restrict__ reward_out) {
    const int s    = blockIdx.x * K_ROWS;
    const int tid  = threadIdx.x;
    const int lane = tid & 63, wave = tid >> 6;
    __shared__ float red[2][4][3];

    // ---- prep phase: boundary row (row s-1; block 0 uses row 0, discarded) ----
    const int rp = (s == 0) ? 0 : s - 1;
    {
        const float4* wb = (const float4*)(w + (size_t)rp * N_DIM);
        const float4* yb = (const float4*)(y + (size_t)rp * N_DIM);
        // staged in local scope below
        float4 wv[8], yv[8];
        #pragma unroll
        for (int j = 0; j < 8; ++j) wv[j] = wb[tid + 256 * j];
        #pragma unroll
        for (int j = 0; j < 8; ++j) yv[j] = yb[tid + 256 * j];
        // nothing else; fallthrough handled by main staging below
        // (kept separate to make the pipeline explicit)
        // compute e_prev / dot_prev
        float d = 0.f;
        float4 ep[8];
        #pragma unroll
        for (int j = 0; j < 8; ++j) {
            float4 ev;
            ev.x = wv[j].x * yv[j].x; ev.y = wv[j].y * yv[j].y;
            ev.z = wv[j].z * yv[j].z; ev.w = wv[j].w * yv[j].w;
            d += (ev.x + ev.y) + (ev.z + ev.w);
            ep[j] = ev;
        }
        // stash into the persistent arrays via plain assignment
        // (declared after this block in original; restructure: declare first)
        // -- see below: we declare persistent arrays before this scope instead.
        // This block is re-written below; placeholder comment only.
        (void)d; (void)ep;
    }
    // NOTE: the scoped version above is illustrative; actual implementation:

    float4 wv[8], yv[8];      // staging registers (current row in flight)
    float4 e_prev[8];         // previous row's element rewards
    float  inv_dprev;

    {
        const float4* wb = (const float4*)(w + (size_t)rp * N_DIM);
        const float4* yb = (const float4*)(y + (size_t)rp * N_DIM);
        #pragma unroll
        for (int j = 0; j < 8; ++j) wv[j] = wb[tid + 256 * j];
        #pragma unroll
        for (int j = 0; j < 8; ++j) yv[j] = yb[tid + 256 * j];

        float d = 0.f;
        #pragma unroll
        for (int j = 0; j < 8; ++j) {
            float4 ev;
            ev.x = wv[j].x * yv[j].x; ev.y = wv[j].y * yv[j].y;
            ev.z = wv[j].z * yv[j].z; ev.w = wv[j].w * yv[j].w;
            d += (ev.x + ev.y) + (ev.z + ev.w);
            e_prev[j] = ev;
        }

        // prefetch row s while the reduction runs
        const float4* wc = (const float4*)(w + (size_t)s * N_DIM);
        const float4* yc = (const float4*)(y + (size_t)s * N_DIM);
        #pragma unroll
        for (int j = 0; j < 8; ++j) wv[j] = wc[tid + 256 * j];
        #pragma unroll
        for (int j = 0; j < 8; ++j) yv[j] = yc[tid + 256 * j];

        #pragma unroll
        for (int off = 32; off; off >>= 1) d += __shfl_down(d, off);
        if (lane == 0) red[0][wave][0] = d;
        __syncthreads();
        inv_dprev = 1.0f / ((red[0][0][0] + red[0][1][0]) + (red[0][2][0] + red[0][3][0]));
    }

    // ---- main phases: rows s .. s+K_ROWS-1, pipelined ----
    #pragma unroll 1
    for (int k = 0; k < K_ROWS; ++k) {
        const int r = s + k;

        float d = 0.f, it = 0.f, cm = 0.f;
        #pragma unroll
        for (int j = 0; j < 8; ++j) {
            float4 ev;
            ev.x = wv[j].x * yv[j].x; ev.y = wv[j].y * yv[j].y;
            ev.z = wv[j].z * yv[j].z; ev.w = wv[j].w * yv[j].w;
            d  += (ev.x + ev.y) + (ev.z + ev.w);
            it += (fminf(ev.x, 0.f) + fminf(ev.y, 0.f)) +
                  (fminf(ev.z, 0.f) + fminf(ev.w, 0.f));
            cm += (fabsf(fmaf(e_prev[j].x, inv_dprev, -wv[j].x)) +
                   fabsf(fmaf(e_prev[j].y, inv_dprev, -wv[j].y))) +
                  (fabsf(fmaf(e_prev[j].z, inv_dprev, -wv[j].z)) +
                   fabsf(fmaf(e_prev[j].w, inv_dprev, -wv[j].w)));
            e_prev[j] = ev;
        }

        // issue next row's loads before the reduction (overlap HBM w/ shfl chain)
        if (k + 1 < K_ROWS) {
            const float4* wn = (const float4*)(w + (size_t)(r + 1) * N_DIM);
            const float4* yn = (const float4*)(y + (size_t)(r + 1) * N_DIM);
            #pragma unroll
            for (int j = 0; j < 8; ++j) wv[j] = wn[tid + 256 * j];
            #pragma unroll
            for (int j = 0; j < 8; ++j) yv[j] = yn[tid + 256 * j];
        }

        #pragma unroll
        for (int off = 32; off; off >>= 1) {
            d  += __shfl_down(d,  off);
            it += __shfl_down(it, off);
            cm += __shfl_down(cm, off);
        }
        const int pb = (k + 1) & 1;   // double-buffer: 1 barrier per phase
        if (lane == 0) { red[pb][wave][0] = d; red[pb][wave][1] = it; red[pb][wave][2] = cm; }
        __syncthreads();
        const float dot_r = (red[pb][0][0] + red[pb][1][0]) + (red[pb][2][0] + red[pb][3][0]);
        const float int_r = ((red[pb][0][1] + red[pb][1][1]) + (red[pb][2][1] + red[pb][3][1])) * kInterest;
        const float comm  = (red[pb][0][2] + red[pb][1][2]) + (red[pb][2][2] + red[pb][3][2]);
        const float pc = (r == 0) ? 1.0f : fmaf(-comm, kCommission, 1.0f);
        if (tid == 0) reward_out[r] = dot_r * pc + int_r;
        inv_dprev = 1.0f / dot_r;
    }
}

// ---------------------------------------------------------------------------
// Finalize (unchanged, passing): 1 block, 1024 threads, 4 rewards/thread.
// ---------------------------------------------------------------------------
__global__ __launch_bounds__(1024) void finalize_kernel(const float* __restrict__ reward,
                                                        float* __restrict__ out) {
    const int T = 1024, PER = B_DIM / T;   // 4
    const int tid = threadIdx.x;
    const int lane = tid & 63, wave = tid >> 6;

    float r[PER], lc[PER];
    float csum = 0.f;
    #pragma unroll
    for (int j = 0; j < PER; ++j) {
        r[j] = reward[tid * PER + j];
        csum += logf(r[j]);
        lc[j] = csum;
    }

    // block inclusive scan of per-thread log sums
    float v = csum;
    #pragma unroll
    for (int off = 1; off < 64; off <<= 1) {
        float t = __shfl_up(v, off);
        if (lane >= off) v += t;
    }
    __shared__ float wsum[16];
    __shared__ float woff[17];
    if (lane == 63) wsum[wave] = v;
    __syncthreads();
    if (tid == 0) {
        float acc = 0.f;
        for (int i = 0; i < 16; ++i) { woff[i] = acc; acc += wsum[i]; }
        woff[16] = acc;
    }
    __syncthreads();
    float ev = __shfl_up(v, 1);
    if (lane == 0) ev = 0.f;
    const float excl = woff[wave] + ev;
    float S[PER];
    #pragma unroll
    for (int j = 0; j < PER; ++j) S[j] = excl + lc[j];
    const float total_logs = woff[16];

    // block prefix-max over S
    float rm = -INFINITY;
    float cmax[PER];
    #pragma unroll
    for (int j = 0; j < PER; ++j) { rm = fmaxf(rm, S[j]); cmax[j] = rm; }
    float mv = rm;
    #pragma unroll
    for (int off = 1; off < 64; off <<= 1) {
        float t = __shfl_up(mv, off);
        if (lane >= off) mv = fmaxf(mv, t);
    }
    __shared__ float wmax[16];
    __shared__ float wmoff[16];
    if (lane == 63) wmax[wave] = mv;
    __syncthreads();
    if (tid == 0) {
        float acc = -INFINITY;
        for (int i = 0; i < 16; ++i) { wmoff[i] = acc; acc = fmaxf(acc, wmax[i]); }
    }
    __syncthreads();
    float emv = __shfl_up(mv, 1);
    if (lane == 0) emv = -INFINITY;
    const float mexcl = fmaxf(wmoff[wave], emv);

    float ddmax = 0.f;
    #pragma unroll
    for (int j = 0; j < PER; ++j) {
        float M = fmaxf(mexcl, cmax[j]);
        ddmax = fmaxf(ddmax, 1.0f - expf(S[j] - M));
    }
    #pragma unroll
    for (int off = 32; off; off >>= 1) ddmax = fmaxf(ddmax, __shfl_down(ddmax, off));
    __shared__ float wdd[16];
    if (lane == 0) wdd[wave] = ddmax;

    // double-precision two-pass mean/var for SR
    double sr_ = 0.0;
    #pragma unroll
    for (int j = 0; j < PER; ++j) sr_ += (double)r[j];
    #pragma unroll
    for (int off = 32; off; off >>= 1) sr_ += __shfl_down(sr_, off);
    __shared__ double wsr[16];
    if (lane == 0) wsr[wave] = sr_;
    __syncthreads();
    __shared__ double mean_sh;
    if (tid == 0) {
        double sm = 0.0;
        for (int i = 0; i < 16; ++i) sm += wsr[i];
        mean_sh = sm / (double)B_DIM;
    }
    __syncthreads();
    const double mean = mean_sh;
    double sq = 0.0;
    #pragma unroll
    for (int j = 0; j < PER; ++j) { double dd = (double)r[j] - mean; sq += dd * dd; }
    #pragma unroll
    for (int off = 32; off; off >>= 1) sq += __shfl_down(sq, off);
    __shared__ double wsq[16];
    if (lane == 0) wsq[wave] = sq;
    __syncthreads();

    if (tid == 0) {
        double sm = 0.0;
        for (int i = 0; i < 16; ++i) sm += wsq[i];
        double var = sm / (double)(B_DIM - 1);
        double SR = (mean - 1.0) / sqrt(var);
        float mdd = 0.f;
        for (int i = 0; i < 16; ++i) mdd = fmaxf(mdd, wdd[i]);
        out[0] = -total_logs / (float)B_DIM;
        out[1] = expf(total_logs);
        out[2] = (float)SR;
        out[3] = mdd;
    }
}

// ---------------------------------------------------------------------------
extern "C" void kernel_launch(void* const* d_in, const int* in_sizes, int n_in,
                              void* d_out, int out_size, void* d_ws, size_t ws_size,
                              hipStream_t stream) {
    const float* w = (const float*)d_in[0];   // (B,1,N)
    const float* y = (const float*)d_in[1];   // (B,N,1)
    float* out = (float*)d_out;
    float* rew = (float*)d_ws;                // B floats

    fused_reward_kernel<<<NBLK, 256, 0, stream>>>(w, y, rew);
    finalize_kernel<<<1, 1024, 0, stream>>>(rew, out);
}